// Round 9
// baseline (211.657 us; speedup 1.0000x reference)
//
#include <hip/hip_runtime.h>
#include <math.h>

#define N_USERS 1000000
#define N_ITEMS 100000
#define EMB 16
#define OUTD 16
#define NH 4
#define HID 32
#define BB 8192
#define SS 200
#define LL 50
#define NSUPP 50000

typedef float v4f __attribute__((ext_vector_type(4)));
typedef _Float16 h2 __attribute__((ext_vector_type(2)));
typedef _Float16 h4 __attribute__((ext_vector_type(4)));

// within-wave LDS ordering fence (lockstep wave; drain DS ops; keep the
// sched_barrier so the compiler can't hoist dependent ops above the wait)
#define WAVE_SYNC() do { asm volatile("s_waitcnt lgkmcnt(0)" ::: "memory"); \
                         __builtin_amdgcn_sched_barrier(0); } while (0)

// ---------------------------------------------------------------------------
// Kernel 1 (prep) — R7 form (R8 proved moving branch-2 into the hot kernel
// puts the item_emb first-touch miss chain on the critical path: FETCH 21->41
// MB, +17.5 us; reverted):
//  blocks [0, 3125):         fp16 user table: tbl[n] = (fp16) user_emb[supp[n]]
//  blocks [3125, 3125+2048): user_init -> q -> q~ (q~_e = sum_o wk[h][e][o] q_o)
//  block  3125+2048:         Wkv[h] = wk[h] @ wv[h]  (16x16 per head, fp32)
// Algebra: score = u . q~ ; ctx = sum_s w u ; gat = (ctx @ Wkv)/l.
// K never materialized; gathered table = 1.6 MB shared by ALL heads ->
// L2-resident on every XCD (R7 FETCH = index stream only confirms).
// ---------------------------------------------------------------------------
__global__ __launch_bounds__(256) void prep_kernel(
    const float* __restrict__ user_emb,
    const int*   __restrict__ supp_users,
    const float* __restrict__ wk,
    const float* __restrict__ wq,
    const float* __restrict__ wv,
    const float* __restrict__ item_emb,
    const int*   __restrict__ history,
    const int*   __restrict__ history_len,
    _Float16*    __restrict__ tbl,
    _Float16*    __restrict__ qtbuf,
    float*       __restrict__ Wkv)
{
    __shared__ float s_ui[4][EMB];
    __shared__ float s_wq[NH * EMB * OUTD];
    __shared__ float s_wk[NH * EMB * OUTD];
    __shared__ float s_q[4][NH * OUTD];

    int t = threadIdx.x;
    if (blockIdx.x < NSUPP / 16) {
        // ---- fp16 user table (16 rows / block) ----
        int n0 = blockIdx.x * 16;
        int ul = t >> 4, e = t & 15;
        int row = supp_users[n0 + ul];
        tbl[(size_t)(n0 + ul) * EMB + e] =
            (_Float16)user_emb[(size_t)row * EMB + e];
    } else if (blockIdx.x < NSUPP / 16 + BB / 4) {
        // ---- user_init -> q -> q~ ----
        for (int i = t; i < NH * EMB * OUTD; i += 256) {
            s_wq[i] = wq[i];
            s_wk[i] = wk[i];
        }
        int g    = t >> 6;
        int lane = t & 63;
        int l4   = lane >> 4;
        int e    = lane & 15;
        int b    = (blockIdx.x - NSUPP / 16) * 4 + g;

        float sum = 0.f;
        for (int l = l4; l < LL; l += 4) {
            int it = __builtin_nontemporal_load(history + (size_t)b * LL + l);
            sum += item_emb[(size_t)it * EMB + e];
        }
        sum += __shfl_xor(sum, 16);
        sum += __shfl_xor(sum, 32);
        if (lane < EMB) s_ui[g][lane] = sum / (float)history_len[b];
        __syncthreads();

        int h = (t >> 4) & 3;
        int o = t & 15;
        float acc = 0.f;
#pragma unroll
        for (int ee = 0; ee < EMB; ++ee)
            acc += s_ui[g][ee] * s_wq[(h * EMB + ee) * OUTD + o];
        s_q[g][h * OUTD + o] = acc;
        __syncthreads();

        // q~_e = sum_o wk[h][e][o] * q_o
        float qt = 0.f;
#pragma unroll
        for (int oo = 0; oo < OUTD; ++oo)
            qt += s_wk[(h * EMB + o) * OUTD + oo] * s_q[g][h * OUTD + oo];
        qtbuf[((size_t)b * NH + h) * EMB + o] = (_Float16)qt;
    } else {
        // ---- Wkv[h][e][p] = sum_o wk[h][e][o] * wv[h][o][p] ----
        for (int i = t; i < NH * EMB * OUTD; i += 256) {
            int h = i >> 8, e = (i >> 4) & 15, p = i & 15;
            float a = 0.f;
#pragma unroll
            for (int o = 0; o < OUTD; ++o)
                a += wk[(h * EMB + e) * OUTD + o] * wv[(h * OUTD + o) * OUTD + p];
            Wkv[i] = a;
        }
    }
}

// ---------------------------------------------------------------------------
// Kernel 2 (fused attn + epilogue): grid BB/4, 256 threads, wave = head.
// R7 structure verbatim; only change: __launch_bounds__(256, 8) — R2 ran
// this exact gather core at 8 blocks/CU (63% occupancy) on the request-rate
// floor; R7's (256,4) sat at 44%. More resident waves hide the epilogue
// tail + shfl-reduce bubbles (the floor itself is occupancy-invariant).
// Attn core: quad-cooperative gather at the shared 1.6 MB u-table. Floor
// (measured R0/R2/R3): 6.55M unique random 32-B rows x ~4.1 cy/row/CU,
// invariant to bytes/row, lanes/row, instr count.
// ---------------------------------------------------------------------------
__global__ __launch_bounds__(256, 8) void attn_epi_kernel(
    const _Float16* __restrict__ tbl,
    const _Float16* __restrict__ qtbuf,
    const int*   __restrict__ sample_index,
    const float* __restrict__ Wkv,
    const float* __restrict__ item_emb,
    const float* __restrict__ w_out,
    const float* __restrict__ l1_w, const float* __restrict__ l1_b,
    const float* __restrict__ l2_w, const float* __restrict__ l2_b,
    const float* __restrict__ l3_w, const float* __restrict__ l3_b,
    const float* __restrict__ user_bias, const float* __restrict__ item_bias,
    const int*   __restrict__ x,
    float*       __restrict__ out)
{
    __shared__ float s_gat[4][NH * OUTD];
    __shared__ float s_ue[4][OUTD];
    __shared__ float s_ie[4][EMB];
    __shared__ float s_x1[4][HID];
    __shared__ float s_x2[4][HID / 2];

    int h    = threadIdx.x >> 6;    // wave = head
    int lane = threadIdx.x & 63;
    int g    = lane >> 2;           // row slot within a round (16 per round)
    int qt   = lane & 3;            // which 8-B quarter of the 32-B row

    const h4* U4 = (const h4*)tbl;

    for (int bl = 0; bl < 4; ++bl) {
        int b = blockIdx.x * 4 + bl;

        // coalesced preload of all 200 indices (nt: pure stream)
        const int* si = sample_index + ((size_t)h * BB + b) * SS;
        int pre0 = __builtin_nontemporal_load(si + lane);
        int pre1 = __builtin_nontemporal_load(si + lane + 64);
        int pre2 = __builtin_nontemporal_load(si + lane + 128);
        int pre3 = (lane < 8) ? __builtin_nontemporal_load(si + lane + 192) : 0;

        // this lane's quarter of q~ (fp16)
        h4 qh = ((const h4*)(qtbuf + ((size_t)b * NH + h) * EMB))[qt];
        h2 qlo = {qh.x, qh.y};
        h2 qhi = {qh.z, qh.w};

        // broadcast per-round row index to the owning quad
        int idx[13];
#pragma unroll
        for (int r = 0; r < 13; ++r) {
            int pre = (r < 4) ? pre0 : (r < 8) ? pre1 : (r < 12) ? pre2 : pre3;
            idx[r] = __shfl(pre, (r & 3) * 16 + g, 64);
        }

        // all 13 quad-cooperative gathers in flight (packed fp16)
        h4 kq[13];
#pragma unroll
        for (int r = 0; r < 13; ++r)
            kq[r] = U4[(size_t)idx[r] * 4 + qt];

        // single fused pass: quarter-dot, quad reduce, exp, accumulate
        float l = 0.f;
        v4f c = {0.f, 0.f, 0.f, 0.f};
#pragma unroll
        for (int r = 0; r < 13; ++r) {
            h2 klo = {kq[r].x, kq[r].y};
            h2 khi = {kq[r].z, kq[r].w};
            float p = __builtin_amdgcn_fdot2(klo, qlo,
                      __builtin_amdgcn_fdot2(khi, qhi, 0.f, false), false);
            p += __shfl_xor(p, 1);
            p += __shfl_xor(p, 2);
            float w = __expf(p);              // no-max softmax: |u.q~| ~ 1e-5
            if (r == 12) w = (g < 8) ? w : 0.f;  // round 12: s=192..207 mask
            l += w;
            c += w * __builtin_convertvector(kq[r], v4f);
        }
#pragma unroll
        for (int off = 4; off < 64; off <<= 1) {  // cross-group, qt-preserving
            l   += __shfl_xor(l, off);
            c.x += __shfl_xor(c.x, off);
            c.y += __shfl_xor(c.y, off);
            c.z += __shfl_xor(c.z, off);
            c.w += __shfl_xor(c.w, off);
        }
        float inv = 1.f / l;

        // gat[p=g] = sum_e cu[e] * Wkv[h][e][g] / l ; lane owns e = qt*4..+3
        float part = c.x * Wkv[((size_t)h * EMB + qt * 4 + 0) * OUTD + g]
                   + c.y * Wkv[((size_t)h * EMB + qt * 4 + 1) * OUTD + g]
                   + c.z * Wkv[((size_t)h * EMB + qt * 4 + 2) * OUTD + g]
                   + c.w * Wkv[((size_t)h * EMB + qt * 4 + 3) * OUTD + g];
        part += __shfl_xor(part, 1);
        part += __shfl_xor(part, 2);
        if (qt == 0)
            s_gat[bl][h * OUTD + g] = part * inv;
    }
    __syncthreads();   // s_gat complete for all 4 b's x 4 heads

    // ---- per-wave epilogue: wave h handles b_local = h (wave-private) ----
    int b   = blockIdx.x * 4 + h;
    int uid = x[(size_t)b * 2 + 0];
    int iid = x[(size_t)b * 2 + 1];

    if (lane < EMB) s_ie[h][lane] = item_emb[(size_t)iid * EMB + lane];
    if (lane < OUTD) {
        float acc = 0.f;
#pragma unroll
        for (int j = 0; j < NH * OUTD; ++j)
            acc += s_gat[h][j] * w_out[j * OUTD + lane];
        s_ue[h][lane] = acc;
    }
    WAVE_SYNC();

    if (lane < HID) {
        float acc = l1_b[lane];
#pragma unroll
        for (int i = 0; i < EMB; ++i) {
            float ue = s_ue[h][i], ie = s_ie[h][i];
            acc += ue * l1_w[i * HID + lane]
                 + ie * l1_w[(EMB + i) * HID + lane]
                 + ue * ie * l1_w[(2 * EMB + i) * HID + lane];
        }
        s_x1[h][lane] = tanhf(acc);
    }
    WAVE_SYNC();

    if (lane < HID / 2) {
        float acc = l2_b[lane];
#pragma unroll
        for (int j = 0; j < HID; ++j)
            acc += s_x1[h][j] * l2_w[j * (HID / 2) + lane];
        s_x2[h][lane] = tanhf(acc);
    }
    WAVE_SYNC();

    if (lane == 0) {
        float x3 = l3_b[0];
#pragma unroll
        for (int j = 0; j < HID / 2; ++j) x3 += s_x2[h][j] * l3_w[j];
        float ratings = 0.f;
#pragma unroll
        for (int o = 0; o < OUTD; ++o) ratings += s_ue[h][o] * s_ie[h][o];
        out[b] = 0.5f * (ratings + x3) + user_bias[uid] + item_bias[iid];
    }
}

// ---------------------------------------------------------------------------
extern "C" void kernel_launch(void* const* d_in, const int* in_sizes, int n_in,
                              void* d_out, int out_size, void* d_ws, size_t ws_size,
                              hipStream_t stream) {
    const float* user_embedding = (const float*)d_in[0];
    const float* item_embedding = (const float*)d_in[1];
    const float* wq             = (const float*)d_in[2];
    const float* wk             = (const float*)d_in[3];
    const float* wv             = (const float*)d_in[4];
    const float* w_out          = (const float*)d_in[5];
    const float* l1_w           = (const float*)d_in[6];
    const float* l1_b           = (const float*)d_in[7];
    const float* l2_w           = (const float*)d_in[8];
    const float* l2_b           = (const float*)d_in[9];
    const float* l3_w           = (const float*)d_in[10];
    const float* l3_b           = (const float*)d_in[11];
    const float* user_bias      = (const float*)d_in[12];
    const float* item_bias      = (const float*)d_in[13];
    const int*   x              = (const int*)d_in[14];
    const int*   history        = (const int*)d_in[15];
    const int*   history_len    = (const int*)d_in[16];
    const int*   supp_users     = (const int*)d_in[17];
    const int*   sample_index   = (const int*)d_in[18];
    float* out = (float*)d_out;

    char* ws = (char*)d_ws;
    _Float16* tbl = (_Float16*)ws;                       // 1.6 MB
    ws += (size_t)NSUPP * EMB * sizeof(_Float16);
    _Float16* qtbuf = (_Float16*)ws;                     // 1 MB
    ws += (size_t)BB * NH * EMB * sizeof(_Float16);
    float* Wkv = (float*)ws;                             // 4 KB

    prep_kernel<<<NSUPP / 16 + BB / 4 + 1, 256, 0, stream>>>(
        user_embedding, supp_users, wk, wq, wv,
        item_embedding, history, history_len, tbl, qtbuf, Wkv);
    attn_epi_kernel<<<BB / 4, 256, 0, stream>>>(
        tbl, qtbuf, sample_index, Wkv, item_embedding, w_out,
        l1_w, l1_b, l2_w, l2_b, l3_w, l3_b,
        user_bias, item_bias, x, out);
}

// Round 10
// 201.908 us; speedup vs baseline: 1.0483x; 1.0483x over previous
//
#include <hip/hip_runtime.h>
#include <math.h>

#define N_USERS 1000000
#define N_ITEMS 100000
#define EMB 16
#define OUTD 16
#define NH 4
#define HID 32
#define BB 8192
#define SS 200
#define LL 50
#define NSUPP 50000

typedef float v4f __attribute__((ext_vector_type(4)));
typedef _Float16 h2 __attribute__((ext_vector_type(2)));
typedef _Float16 h4 __attribute__((ext_vector_type(4)));

// within-wave LDS ordering fence (lockstep wave; drain DS ops; keep the
// sched_barrier so the compiler can't hoist dependent ops above the wait)
#define WAVE_SYNC() do { asm volatile("s_waitcnt lgkmcnt(0)" ::: "memory"); \
                         __builtin_amdgcn_sched_barrier(0); } while (0)

// ---------------------------------------------------------------------------
// Kernel 1 (prep) — R7 form:
//  blocks [0, 3125):         fp16 user table: tbl[n] = (fp16) user_emb[supp[n]]
//  blocks [3125, 3125+2048): user_init -> q -> q~ (q~_e = sum_o wk[h][e][o] q_o)
//  block  3125+2048:         Wkv[h] = wk[h] @ wv[h]  (16x16 per head, fp32)
// Algebra: score = u . q~ ; ctx = sum_s w u ; gat = (ctx @ Wkv)/l.
// K never materialized; gathered table = 1.6 MB shared by ALL heads ->
// L2-resident on every XCD (R7 FETCH = index stream only confirms).
// R8 proved moving branch-2 into the hot kernel puts the item_emb
// first-touch miss chain on the critical path (FETCH 21->41 MB, +17.5 us).
// ---------------------------------------------------------------------------
__global__ __launch_bounds__(256) void prep_kernel(
    const float* __restrict__ user_emb,
    const int*   __restrict__ supp_users,
    const float* __restrict__ wk,
    const float* __restrict__ wq,
    const float* __restrict__ wv,
    const float* __restrict__ item_emb,
    const int*   __restrict__ history,
    const int*   __restrict__ history_len,
    _Float16*    __restrict__ tbl,
    _Float16*    __restrict__ qtbuf,
    float*       __restrict__ Wkv)
{
    __shared__ float s_ui[4][EMB];
    __shared__ float s_wq[NH * EMB * OUTD];
    __shared__ float s_wk[NH * EMB * OUTD];
    __shared__ float s_q[4][NH * OUTD];

    int t = threadIdx.x;
    if (blockIdx.x < NSUPP / 16) {
        // ---- fp16 user table (16 rows / block) ----
        int n0 = blockIdx.x * 16;
        int ul = t >> 4, e = t & 15;
        int row = supp_users[n0 + ul];
        tbl[(size_t)(n0 + ul) * EMB + e] =
            (_Float16)user_emb[(size_t)row * EMB + e];
    } else if (blockIdx.x < NSUPP / 16 + BB / 4) {
        // ---- user_init -> q -> q~ ----
        for (int i = t; i < NH * EMB * OUTD; i += 256) {
            s_wq[i] = wq[i];
            s_wk[i] = wk[i];
        }
        int g    = t >> 6;
        int lane = t & 63;
        int l4   = lane >> 4;
        int e    = lane & 15;
        int b    = (blockIdx.x - NSUPP / 16) * 4 + g;

        float sum = 0.f;
        for (int l = l4; l < LL; l += 4) {
            int it = __builtin_nontemporal_load(history + (size_t)b * LL + l);
            sum += item_emb[(size_t)it * EMB + e];
        }
        sum += __shfl_xor(sum, 16);
        sum += __shfl_xor(sum, 32);
        if (lane < EMB) s_ui[g][lane] = sum / (float)history_len[b];
        __syncthreads();

        int h = (t >> 4) & 3;
        int o = t & 15;
        float acc = 0.f;
#pragma unroll
        for (int ee = 0; ee < EMB; ++ee)
            acc += s_ui[g][ee] * s_wq[(h * EMB + ee) * OUTD + o];
        s_q[g][h * OUTD + o] = acc;
        __syncthreads();

        // q~_e = sum_o wk[h][e][o] * q_o
        float qt = 0.f;
#pragma unroll
        for (int oo = 0; oo < OUTD; ++oo)
            qt += s_wk[(h * EMB + o) * OUTD + oo] * s_q[g][h * OUTD + oo];
        qtbuf[((size_t)b * NH + h) * EMB + o] = (_Float16)qt;
    } else {
        // ---- Wkv[h][e][p] = sum_o wk[h][e][o] * wv[h][o][p] ----
        for (int i = t; i < NH * EMB * OUTD; i += 256) {
            int h = i >> 8, e = (i >> 4) & 15, p = i & 15;
            float a = 0.f;
#pragma unroll
            for (int o = 0; o < OUTD; ++o)
                a += wk[(h * EMB + e) * OUTD + o] * wv[(h * OUTD + o) * OUTD + p];
            Wkv[i] = a;
        }
    }
}

// ---------------------------------------------------------------------------
// Kernel 2 (fused attn + epilogue): grid BB/4, 256 threads, wave = head.
// R7 structure VERBATIM, including __launch_bounds__(256, 4): R9 measured
// that (256,8) forces VGPR 40->32 and spills to scratch (WRITE 64KB->8.8MB,
// attn_epi 53.5->61 us) despite occupancy 44->65%. (256,4) is the measured
// optimum of this structure.
// Attn core: quad-cooperative gather at the shared 1.6 MB u-table. Floor
// (measured R0/R2/R3): 6.55M unique random 32-B rows x ~4.1 cy/row/CU,
// invariant to bytes/row, lanes/row, instr count, occupancy.
// ---------------------------------------------------------------------------
__global__ __launch_bounds__(256, 4) void attn_epi_kernel(
    const _Float16* __restrict__ tbl,
    const _Float16* __restrict__ qtbuf,
    const int*   __restrict__ sample_index,
    const float* __restrict__ Wkv,
    const float* __restrict__ item_emb,
    const float* __restrict__ w_out,
    const float* __restrict__ l1_w, const float* __restrict__ l1_b,
    const float* __restrict__ l2_w, const float* __restrict__ l2_b,
    const float* __restrict__ l3_w, const float* __restrict__ l3_b,
    const float* __restrict__ user_bias, const float* __restrict__ item_bias,
    const int*   __restrict__ x,
    float*       __restrict__ out)
{
    __shared__ float s_gat[4][NH * OUTD];
    __shared__ float s_ue[4][OUTD];
    __shared__ float s_ie[4][EMB];
    __shared__ float s_x1[4][HID];
    __shared__ float s_x2[4][HID / 2];

    int h    = threadIdx.x >> 6;    // wave = head
    int lane = threadIdx.x & 63;
    int g    = lane >> 2;           // row slot within a round (16 per round)
    int qt   = lane & 3;            // which 8-B quarter of the 32-B row

    const h4* U4 = (const h4*)tbl;

    for (int bl = 0; bl < 4; ++bl) {
        int b = blockIdx.x * 4 + bl;

        // coalesced preload of all 200 indices (nt: pure stream)
        const int* si = sample_index + ((size_t)h * BB + b) * SS;
        int pre0 = __builtin_nontemporal_load(si + lane);
        int pre1 = __builtin_nontemporal_load(si + lane + 64);
        int pre2 = __builtin_nontemporal_load(si + lane + 128);
        int pre3 = (lane < 8) ? __builtin_nontemporal_load(si + lane + 192) : 0;

        // this lane's quarter of q~ (fp16)
        h4 qh = ((const h4*)(qtbuf + ((size_t)b * NH + h) * EMB))[qt];
        h2 qlo = {qh.x, qh.y};
        h2 qhi = {qh.z, qh.w};

        // broadcast per-round row index to the owning quad
        int idx[13];
#pragma unroll
        for (int r = 0; r < 13; ++r) {
            int pre = (r < 4) ? pre0 : (r < 8) ? pre1 : (r < 12) ? pre2 : pre3;
            idx[r] = __shfl(pre, (r & 3) * 16 + g, 64);
        }

        // all 13 quad-cooperative gathers in flight (packed fp16)
        h4 kq[13];
#pragma unroll
        for (int r = 0; r < 13; ++r)
            kq[r] = U4[(size_t)idx[r] * 4 + qt];

        // single fused pass: quarter-dot, quad reduce, exp, accumulate
        float l = 0.f;
        v4f c = {0.f, 0.f, 0.f, 0.f};
#pragma unroll
        for (int r = 0; r < 13; ++r) {
            h2 klo = {kq[r].x, kq[r].y};
            h2 khi = {kq[r].z, kq[r].w};
            float p = __builtin_amdgcn_fdot2(klo, qlo,
                      __builtin_amdgcn_fdot2(khi, qhi, 0.f, false), false);
            p += __shfl_xor(p, 1);
            p += __shfl_xor(p, 2);
            float w = __expf(p);              // no-max softmax: |u.q~| ~ 1e-5
            if (r == 12) w = (g < 8) ? w : 0.f;  // round 12: s=192..207 mask
            l += w;
            c += w * __builtin_convertvector(kq[r], v4f);
        }
#pragma unroll
        for (int off = 4; off < 64; off <<= 1) {  // cross-group, qt-preserving
            l   += __shfl_xor(l, off);
            c.x += __shfl_xor(c.x, off);
            c.y += __shfl_xor(c.y, off);
            c.z += __shfl_xor(c.z, off);
            c.w += __shfl_xor(c.w, off);
        }
        float inv = 1.f / l;

        // gat[p=g] = sum_e cu[e] * Wkv[h][e][g] / l ; lane owns e = qt*4..+3
        float part = c.x * Wkv[((size_t)h * EMB + qt * 4 + 0) * OUTD + g]
                   + c.y * Wkv[((size_t)h * EMB + qt * 4 + 1) * OUTD + g]
                   + c.z * Wkv[((size_t)h * EMB + qt * 4 + 2) * OUTD + g]
                   + c.w * Wkv[((size_t)h * EMB + qt * 4 + 3) * OUTD + g];
        part += __shfl_xor(part, 1);
        part += __shfl_xor(part, 2);
        if (qt == 0)
            s_gat[bl][h * OUTD + g] = part * inv;
    }
    __syncthreads();   // s_gat complete for all 4 b's x 4 heads

    // ---- per-wave epilogue: wave h handles b_local = h (wave-private) ----
    int b   = blockIdx.x * 4 + h;
    int uid = x[(size_t)b * 2 + 0];
    int iid = x[(size_t)b * 2 + 1];

    if (lane < EMB) s_ie[h][lane] = item_emb[(size_t)iid * EMB + lane];
    if (lane < OUTD) {
        float acc = 0.f;
#pragma unroll
        for (int j = 0; j < NH * OUTD; ++j)
            acc += s_gat[h][j] * w_out[j * OUTD + lane];
        s_ue[h][lane] = acc;
    }
    WAVE_SYNC();

    if (lane < HID) {
        float acc = l1_b[lane];
#pragma unroll
        for (int i = 0; i < EMB; ++i) {
            float ue = s_ue[h][i], ie = s_ie[h][i];
            acc += ue * l1_w[i * HID + lane]
                 + ie * l1_w[(EMB + i) * HID + lane]
                 + ue * ie * l1_w[(2 * EMB + i) * HID + lane];
        }
        s_x1[h][lane] = tanhf(acc);
    }
    WAVE_SYNC();

    if (lane < HID / 2) {
        float acc = l2_b[lane];
#pragma unroll
        for (int j = 0; j < HID; ++j)
            acc += s_x1[h][j] * l2_w[j * (HID / 2) + lane];
        s_x2[h][lane] = tanhf(acc);
    }
    WAVE_SYNC();

    if (lane == 0) {
        float x3 = l3_b[0];
#pragma unroll
        for (int j = 0; j < HID / 2; ++j) x3 += s_x2[h][j] * l3_w[j];
        float ratings = 0.f;
#pragma unroll
        for (int o = 0; o < OUTD; ++o) ratings += s_ue[h][o] * s_ie[h][o];
        out[b] = 0.5f * (ratings + x3) + user_bias[uid] + item_bias[iid];
    }
}

// ---------------------------------------------------------------------------
extern "C" void kernel_launch(void* const* d_in, const int* in_sizes, int n_in,
                              void* d_out, int out_size, void* d_ws, size_t ws_size,
                              hipStream_t stream) {
    const float* user_embedding = (const float*)d_in[0];
    const float* item_embedding = (const float*)d_in[1];
    const float* wq             = (const float*)d_in[2];
    const float* wk             = (const float*)d_in[3];
    const float* wv             = (const float*)d_in[4];
    const float* w_out          = (const float*)d_in[5];
    const float* l1_w           = (const float*)d_in[6];
    const float* l1_b           = (const float*)d_in[7];
    const float* l2_w           = (const float*)d_in[8];
    const float* l2_b           = (const float*)d_in[9];
    const float* l3_w           = (const float*)d_in[10];
    const float* l3_b           = (const float*)d_in[11];
    const float* user_bias      = (const float*)d_in[12];
    const float* item_bias      = (const float*)d_in[13];
    const int*   x              = (const int*)d_in[14];
    const int*   history        = (const int*)d_in[15];
    const int*   history_len    = (const int*)d_in[16];
    const int*   supp_users     = (const int*)d_in[17];
    const int*   sample_index   = (const int*)d_in[18];
    float* out = (float*)d_out;

    char* ws = (char*)d_ws;
    _Float16* tbl = (_Float16*)ws;                       // 1.6 MB
    ws += (size_t)NSUPP * EMB * sizeof(_Float16);
    _Float16* qtbuf = (_Float16*)ws;                     // 1 MB
    ws += (size_t)BB * NH * EMB * sizeof(_Float16);
    float* Wkv = (float*)ws;                             // 4 KB

    prep_kernel<<<NSUPP / 16 + BB / 4 + 1, 256, 0, stream>>>(
        user_embedding, supp_users, wk, wq, wv,
        item_embedding, history, history_len, tbl, qtbuf, Wkv);
    attn_epi_kernel<<<BB / 4, 256, 0, stream>>>(
        tbl, qtbuf, sample_index, Wkv, item_embedding, w_out,
        l1_w, l1_b, l2_w, l2_b, l3_w, l3_b,
        user_bias, item_bias, x, out);
}